// Round 1
// baseline (78.492 us; speedup 1.0000x reference)
//
#include <hip/hip_runtime.h>

#define N 8192
#define F 256
#define D 64

// ---------------------------------------------------------------------------
// K1: sf = seq@W0 (fp32), f1 = sf@w1+b1, f2 = sf@w2+b2
// 256 blocks x 256 thr, 32 rows/block. W0 (64KB) + padded seq rows (33KB) in LDS.
// thread: cg=t&15 owns 4 cols, rg=t>>4 owns 2 rows.
// ---------------------------------------------------------------------------
__global__ __launch_bounds__(256) void k_proj(
    const float* __restrict__ seq, const float* __restrict__ W0,
    const float* __restrict__ w1, const float* __restrict__ b1,
    const float* __restrict__ w2, const float* __restrict__ b2,
    float* __restrict__ sf, float* __restrict__ f1, float* __restrict__ f2) {
  __shared__ __align__(16) float lw0[F * D];      // 64 KB, [256][64]
  __shared__ __align__(16) float srow[32 * 260];  // 33.3 KB, pad 260 -> conflict-free
  const int t = threadIdx.x;
  {
    const float4* g = (const float4*)W0;
    float4* l = (float4*)lw0;
    #pragma unroll
    for (int i = 0; i < 16; ++i) l[t + i * 256] = g[t + i * 256];
  }
  const int base = blockIdx.x * 32;
  {
    const float4* g = (const float4*)(seq + (size_t)base * F);
    #pragma unroll
    for (int i = 0; i < 8; ++i) {
      int idx = t + i * 256;              // float4 index within 32x256 tile
      int r = idx >> 6, c4 = idx & 63;
      *(float4*)(srow + r * 260 + c4 * 4) = g[idx];
    }
  }
  __syncthreads();
  const int cg = t & 15, rg = t >> 4;
  const int r0 = rg * 2;
  float acc0[4] = {0.f, 0.f, 0.f, 0.f}, acc1[4] = {0.f, 0.f, 0.f, 0.f};
  const float* s0 = srow + r0 * 260;
  const float* s1 = s0 + 260;
  const float* wb = lw0 + cg * 4;
  #pragma unroll 4
  for (int k = 0; k < F; k += 4) {
    float a0[4], a1[4];
    *(float4*)a0 = *(const float4*)(s0 + k);
    *(float4*)a1 = *(const float4*)(s1 + k);
    #pragma unroll
    for (int m = 0; m < 4; ++m) {
      float4 w = *(const float4*)(wb + (k + m) * D);
      acc0[0] += a0[m] * w.x; acc0[1] += a0[m] * w.y;
      acc0[2] += a0[m] * w.z; acc0[3] += a0[m] * w.w;
      acc1[0] += a1[m] * w.x; acc1[1] += a1[m] * w.y;
      acc1[2] += a1[m] * w.z; acc1[3] += a1[m] * w.w;
    }
  }
  const int row0 = base + r0, row1 = row0 + 1;
  *(float4*)(sf + (size_t)row0 * D + cg * 4) = make_float4(acc0[0], acc0[1], acc0[2], acc0[3]);
  *(float4*)(sf + (size_t)row1 * D + cg * 4) = make_float4(acc1[0], acc1[1], acc1[2], acc1[3]);
  float w1v[4], w2v[4];
  *(float4*)w1v = *(const float4*)(w1 + cg * 4);
  *(float4*)w2v = *(const float4*)(w2 + cg * 4);
  float p0 = acc0[0]*w1v[0] + acc0[1]*w1v[1] + acc0[2]*w1v[2] + acc0[3]*w1v[3];
  float q0 = acc0[0]*w2v[0] + acc0[1]*w2v[1] + acc0[2]*w2v[2] + acc0[3]*w2v[3];
  float p1 = acc1[0]*w1v[0] + acc1[1]*w1v[1] + acc1[2]*w1v[2] + acc1[3]*w1v[3];
  float q1 = acc1[0]*w2v[0] + acc1[1]*w2v[1] + acc1[2]*w2v[2] + acc1[3]*w2v[3];
  #pragma unroll
  for (int d = 1; d < 16; d <<= 1) {
    p0 += __shfl_xor(p0, d, 64); q0 += __shfl_xor(q0, d, 64);
    p1 += __shfl_xor(p1, d, 64); q1 += __shfl_xor(q1, d, 64);
  }
  if (cg == 0) {
    f1[row0] = p0 + b1[0]; f2[row0] = q0 + b2[0];
    f1[row1] = p1 + b1[0]; f2[row1] = q1 + b2[0];
  }
}

// ---------------------------------------------------------------------------
// K2: rank[j] = #{k : f2[k] < f2[j] or (== and k<j)}   (exact permutation)
// grid 32x32 tiles of 256, partial counts via int atomicAdd (deterministic).
// ---------------------------------------------------------------------------
__global__ __launch_bounds__(256) void k_rank(const float* __restrict__ f2,
                                              int* __restrict__ rank) {
  __shared__ float fk[256];
  const int t = threadIdx.x;
  const int jt = blockIdx.x & 31, kt = blockIdx.x >> 5;
  const int k0 = kt * 256;
  fk[t] = f2[k0 + t];
  __syncthreads();
  const int j = jt * 256 + t;
  const float fj = f2[j];
  int cnt = 0;
  #pragma unroll 8
  for (int k = 0; k < 256; ++k) {
    float v = fk[k];
    cnt += ((v < fj) || (v == fj && (k0 + k) < j)) ? 1 : 0;
  }
  atomicAdd(&rank[j], cnt);
}

// ---------------------------------------------------------------------------
// K3: scatter into sorted order; u = e^{f2}, u2 = e^{0.2 f2}
// ---------------------------------------------------------------------------
__global__ __launch_bounds__(256) void k_scatter(
    const float* __restrict__ f2, const int* __restrict__ rank,
    float* __restrict__ f2s, float* __restrict__ us, float* __restrict__ u2s,
    int* __restrict__ idxs) {
  const int j = blockIdx.x * 256 + threadIdx.x;
  const float v = f2[j];
  const int r = rank[j];
  f2s[r] = v;
  us[r]  = expf(v);
  u2s[r] = expf(0.2f * v);
  idxs[r] = j;
}

// ---------------------------------------------------------------------------
// K4: cumulative sums over sorted positions (double accumulation).
//  block c<64   : prefNv[k][c] = sum_{pos<k} u2*sf[idx][c]   (k=0..N)
//  block c==64  : prefNs[k]    = sum_{pos<k} u2
//  block 65+c   : sufPv[k][c]  = sum_{pos>=k} u*sf[idx][c]
//  block 129    : sufPs[k]     = sum_{pos>=k} u
// 512 thr, 16 chunks, wave-shfl scan + cross-wave LDS, next-chunk prefetch.
// ---------------------------------------------------------------------------
__global__ __launch_bounds__(512) void k_scan(
    const float* __restrict__ us, const float* __restrict__ u2s,
    const int* __restrict__ idxs, const float* __restrict__ sf,
    float* __restrict__ prefNv, float* __restrict__ prefNs,
    float* __restrict__ sufPv, float* __restrict__ sufPs) {
  const int t = threadIdx.x;
  const int comp = blockIdx.x;           // 0..129
  const bool pref = comp < 65;
  const int c = pref ? comp : comp - 65; // 64 == scalar
  __shared__ double wtot[8];
  const int wid = t >> 6, lane = t & 63;
  double run = 0.0;

  if (pref) {
    if (t == 0) { if (c < 64) prefNv[c] = 0.f; else prefNs[0] = 0.f; }
    int pos = t;
    double v = (c < 64)
        ? (double)u2s[pos] * (double)sf[(size_t)idxs[pos] * D + c]
        : (double)u2s[pos];
    for (int ch = 0; ch < 16; ++ch) {
      double vn = 0.0;
      if (ch + 1 < 16) {
        int p2 = (ch + 1) * 512 + t;
        vn = (c < 64) ? (double)u2s[p2] * (double)sf[(size_t)idxs[p2] * D + c]
                      : (double)u2s[p2];
      }
      double x = v;
      #pragma unroll
      for (int d = 1; d < 64; d <<= 1) {
        double n = __shfl_up(x, d, 64);
        if (lane >= d) x += n;
      }
      if (lane == 63) wtot[wid] = x;
      __syncthreads();
      double add = run;
      for (int w = 0; w < wid; ++w) add += wtot[w];
      double total = 0.0;
      #pragma unroll
      for (int w = 0; w < 8; ++w) total += wtot[w];
      double incl = x + add;
      int p = ch * 512 + t;
      if (c < 64) prefNv[(size_t)(p + 1) * D + c] = (float)incl;
      else        prefNs[p + 1] = (float)incl;
      run += total;
      __syncthreads();
      v = vn;
    }
  } else {
    if (t == 0) { if (c < 64) sufPv[(size_t)N * D + c] = 0.f; else sufPs[N] = 0.f; }
    int pos = 15 * 512 + t;
    double v = (c < 64)
        ? (double)us[pos] * (double)sf[(size_t)idxs[pos] * D + c]
        : (double)us[pos];
    for (int ch = 15; ch >= 0; --ch) {
      double vn = 0.0;
      if (ch > 0) {
        int p2 = (ch - 1) * 512 + t;
        vn = (c < 64) ? (double)us[p2] * (double)sf[(size_t)idxs[p2] * D + c]
                      : (double)us[p2];
      }
      double x = v;
      #pragma unroll
      for (int d = 1; d < 64; d <<= 1) {
        double n = __shfl_up(x, d, 64);
        if (lane >= d) x += n;
      }
      if (lane == 63) wtot[wid] = x;
      __syncthreads();
      double add = 0.0;
      for (int w = 0; w < wid; ++w) add += wtot[w];
      double total = 0.0;
      #pragma unroll
      for (int w = 0; w < 8; ++w) total += wtot[w];
      double incl = x + add;                  // within-chunk inclusive prefix
      double suff = run + total - (incl - v); // sum over p >= pos
      int p = ch * 512 + t;
      if (c < 64) sufPv[(size_t)p * D + c] = (float)suff;
      else        sufPs[p] = (float)suff;
      run += total;
      __syncthreads();
      v = vn;
    }
  }
}

// ---------------------------------------------------------------------------
// K5: per row i: k = upper_bound(sorted f2, -f1[i]);
//     out = (e^a * sufPv[k] + e^{0.2a} * prefNv[k]) / (scalar analog) + bias
// ---------------------------------------------------------------------------
__global__ __launch_bounds__(256) void k_out(
    const float* __restrict__ f1, const float* __restrict__ f2s,
    const float* __restrict__ prefNv, const float* __restrict__ prefNs,
    const float* __restrict__ sufPv, const float* __restrict__ sufPs,
    const float* __restrict__ bias, float* __restrict__ out) {
  __shared__ float sv[N];  // 32 KB sorted f2
  const int t = threadIdx.x;
  #pragma unroll
  for (int i = 0; i < 32; ++i) sv[t + i * 256] = f2s[t + i * 256];
  __syncthreads();
  const int base = blockIdx.x * 32;
  const int c = t & 63;
  const float bc = bias[c];
  for (int it = 0; it < 8; ++it) {
    const int row = base + it * 4 + (t >> 6);
    const float a = f1[row];
    const float tv = -a;
    int lo = 0, hi = N;
    while (lo < hi) {
      int mid = (lo + hi) >> 1;
      if (sv[mid] <= tv) lo = mid + 1; else hi = mid;
    }
    const int k = lo;  // count of (f2 <= -a) == N-branch size
    const float ea = expf(a), ea2 = expf(0.2f * a);
    const float den = ea * sufPs[k] + ea2 * prefNs[k];
    const float num = ea * sufPv[(size_t)k * D + c] + ea2 * prefNv[(size_t)k * D + c];
    out[(size_t)row * D + c] = num / den + bc;
  }
}

extern "C" void kernel_launch(void* const* d_in, const int* in_sizes, int n_in,
                              void* d_out, int out_size, void* d_ws, size_t ws_size,
                              hipStream_t stream) {
  const float* seq  = (const float*)d_in[0];
  const float* W0   = (const float*)d_in[1];
  const float* w1   = (const float*)d_in[2];
  const float* b1   = (const float*)d_in[3];
  const float* w2   = (const float*)d_in[4];
  const float* b2   = (const float*)d_in[5];
  const float* bias = (const float*)d_in[6];
  float* out = (float*)d_out;

  float* ws   = (float*)d_ws;
  float* sf   = ws;                                    // N*D
  float* f1   = sf + (size_t)N * D;                    // N
  float* f2   = f1 + N;                                // N
  float* f2s  = f2 + N;                                // N
  float* us   = f2s + N;                               // N
  float* u2s  = us + N;                                // N
  int*   rank = (int*)(u2s + N);                       // N
  int*   idxs = rank + N;                              // N
  float* prefNv = (float*)(idxs + N);                  // (N+1)*D
  float* sufPv  = prefNv + (size_t)(N + 1) * D;        // (N+1)*D
  float* prefNs = sufPv + (size_t)(N + 1) * D;         // N+1
  float* sufPs  = prefNs + (N + 1);                    // N+1
  // total ~6.6 MB of d_ws

  hipMemsetAsync(rank, 0, N * sizeof(int), stream);
  k_proj<<<N / 32, 256, 0, stream>>>(seq, W0, w1, b1, w2, b2, sf, f1, f2);
  k_rank<<<(N / 256) * (N / 256), 256, 0, stream>>>(f2, rank);
  k_scatter<<<N / 256, 256, 0, stream>>>(f2, rank, f2s, us, u2s, idxs);
  k_scan<<<130, 512, 0, stream>>>(us, u2s, idxs, sf, prefNv, prefNs, sufPv, sufPs);
  k_out<<<N / 32, 256, 0, stream>>>(f1, f2s, prefNv, prefNs, sufPv, sufPs, bias, out);
}